// Round 4
// baseline (244.771 us; speedup 1.0000x reference)
//
#include <hip/hip_runtime.h>
#include <hip/hip_bf16.h>

// MinGRU forward: z=sigmoid(xWz^T), h~=xWh^T, a=1-z+1e-8, b=z*h~, scan h=a*h+b.
// B=4 T=4096 D=1024.
// R4: (1) convert kernel rewritten as coalesced-read -> LDS transpose ->
// coalesced fragment-tiled write (old version was wave-divergent, ~1.4TB/s).
// (2) GEMM A-operand read DIRECTLY from fragment-tiled global (coalesced
// dwordx4), LDS used only for Bz/Bh staging -- cuts LDS BW demand 33%
// (kernel was LDS-BW-bound: 144KB/CU-step vs 128B/cyc => MfmaUtil 30%).
// Scan pass1 fused in GEMM epilogue; pass2 wave64 shuffle scan; pass3 apply.

typedef __bf16 bf16x8 __attribute__((ext_vector_type(8)));
typedef __bf16 bf16x4 __attribute__((ext_vector_type(4)));
typedef float  f32x4  __attribute__((ext_vector_type(4)));

#define BSZ 4
#define TSZ 4096
#define DSZ 1024
#define MSZ (BSZ*TSZ)      // 16384 rows
#define CH  32             // scan chunk length
#define NC  (TSZ/CH)       // 128 chunks per sequence

__device__ __forceinline__ void gload_lds16(const __bf16* g, __bf16* l) {
  __builtin_amdgcn_global_load_lds(
      (const __attribute__((address_space(1))) void*)g,
      (__attribute__((address_space(3))) void*)l, 16, 0, 0);
}

// ---------------- conversion: fp32 row-major -> bf16 fragment-tiled ----------------
// tiled layout: [tile = rowblk*32+kblk][i:8][l:64][j:8] where
//   row = rowblk*128 + i*16 + (l&15), k = kblk*32 + (l>>4)*8 + j
// Block = one 128x32 tile. Coalesced read (8 lanes x 16B = full lines) ->
// LDS (stride 40 bf16, <=2-way banks) -> fragment-order coalesced write.
__global__ __launch_bounds__(256) void convert_tile_kernel(
    const float* __restrict__ X, const float* __restrict__ Wz,
    const float* __restrict__ Wh,
    __bf16* __restrict__ Xc, __bf16* __restrict__ Wzc, __bf16* __restrict__ Whc)
{
  __shared__ __align__(16) __bf16 T[128*40];
  const int bx = blockIdx.x;
  const float* src; __bf16* dst; int tile;
  if (bx < 4096)      { src = X;  dst = Xc;  tile = bx; }
  else if (bx < 4352) { src = Wz; dst = Wzc; tile = bx - 4096; }
  else                { src = Wh; dst = Whc; tile = bx - 4352; }
  const int rowblk = tile >> 5;
  const int kblk   = tile & 31;
  const int t = threadIdx.x;
  #pragma unroll
  for (int rr = 0; rr < 4; ++rr) {
    const int flat = rr*256 + t;         // 0..1023
    const int r    = flat >> 3;          // 0..127
    const int c4   = (flat & 7) * 4;     // 0..28
    float4 v = *(const float4*)(src + (size_t)(rowblk*128 + r)*DSZ + kblk*32 + c4);
    bf16x4 p; p[0]=(__bf16)v.x; p[1]=(__bf16)v.y; p[2]=(__bf16)v.z; p[3]=(__bf16)v.w;
    *(bf16x4*)(T + r*40 + c4) = p;
  }
  __syncthreads();
  #pragma unroll
  for (int half = 0; half < 2; ++half) {
    const int f   = half*2048 + t*8;     // output flat index within tile
    const int i   = f >> 9;
    const int l   = (f >> 3) & 63;
    const int row = i*16 + (l & 15);
    const int k   = (l >> 4) * 8;
    bf16x8 p = *(const bf16x8*)(T + row*40 + k);
    *(bf16x8*)(dst + (size_t)tile*4096 + f) = p;
  }
}

// ---------------- GEMM + gate epilogue + fused per-chunk composition ------------
// block tile 128(M) x 128(N), BK=32; 256 threads = 4 waves in 2x2, each wave 64x64.
// A frags: direct coalesced global loads (fragment-tiled Xc). B: global_load_lds.
// grid dim3(8,128): x=N fast => the 8 N-blocks of an M-tile co-dispatch (Xc L2 reuse).
__global__ __launch_bounds__(256, 2) void gemm_gate_kernel(
    const __bf16* __restrict__ Xc,  const __bf16* __restrict__ Wzc,
    const __bf16* __restrict__ Whc,
    const float* __restrict__ bz, const float* __restrict__ bh,
    __bf16* __restrict__ a_ws, float* __restrict__ b_out,
    float* __restrict__ Aprod, float* __restrict__ Bcomp)
{
  __shared__ __align__(16) __bf16 Bzs[4096];
  __shared__ __align__(16) __bf16 Bhs[4096];

  const int tid  = threadIdx.x;
  const int lane = tid & 63;
  const int wv   = tid >> 6;
  const int wM   = (wv >> 1) * 64;
  const int wN   = (wv & 1) * 64;
  const int wMg  = wM >> 4;
  const int wNg  = wN >> 4;
  const int lr   = lane & 15;
  const int q    = lane >> 4;
  const int wbase = wv * 64;           // wave-uniform

  const int Nb = blockIdx.x;           // 0..7
  const int Mb = blockIdx.y;           // 0..127
  const __bf16* Xb = Xc  + (size_t)Mb * 32 * 4096;
  const __bf16* Zb = Wzc + (size_t)Nb * 32 * 4096;
  const __bf16* Hb = Whc + (size_t)Nb * 32 * 4096;

  f32x4 accz[4][4] = {};
  f32x4 acch[4][4] = {};

  for (int kblk = 0; kblk < 32; ++kblk) {
    __syncthreads();
    const size_t tb = (size_t)kblk * 4096;
    #pragma unroll
    for (int c = 0; c < 2; ++c) {
      const int eo = (c*256 + wbase + lane) * 8;  // per-lane global elem offset
      const int lo = (c*256 + wbase) * 8;         // wave-uniform LDS elem offset
      gload_lds16(Zb + tb + eo, Bzs + lo);
      gload_lds16(Hb + tb + eo, Bhs + lo);
    }
    // A fragments: direct from global, lane-linear (no barrier dependency)
    bf16x8 af[4];
    #pragma unroll
    for (int i = 0; i < 4; ++i)
      af[i] = *(const bf16x8*)(Xb + tb + (size_t)(wMg + i)*512 + lane*8);
    __syncthreads();

    #pragma unroll
    for (int j = 0; j < 4; ++j) {
      bf16x8 bz8 = *(const bf16x8*)(Bzs + (wNg + j)*512 + lane*8);
      bf16x8 bh8 = *(const bf16x8*)(Bhs + (wNg + j)*512 + lane*8);
      #pragma unroll
      for (int i = 0; i < 4; ++i) {
        accz[j][i] = __builtin_amdgcn_mfma_f32_16x16x32_bf16(af[i], bz8, accz[j][i], 0, 0, 0);
        acch[j][i] = __builtin_amdgcn_mfma_f32_16x16x32_bf16(af[i], bh8, acch[j][i], 0, 0, 0);
      }
    }
  }

  // ---- epilogue: gate + store + fused per-chunk affine composition ----
  // C/D layout col=lane&15, row=(lane>>4)*4+reg (verified m89/m91).
  const int M0 = Mb * 128;
  const int N0 = Nb * 128;
  #pragma unroll
  for (int j = 0; j < 4; ++j) {
    const int e = N0 + wN + j*16 + lr;
    const float bzv = bz[e];
    const float bhv = bh[e];
    float Aseg[4], Bseg[4];
    #pragma unroll
    for (int i = 0; i < 4; ++i) {
      const int mbase = M0 + wM + i*16 + q*4;
      float A = 1.0f, Bv = 0.0f;
      #pragma unroll
      for (int r = 0; r < 4; ++r) {
        const size_t idx = (size_t)(mbase + r)*DSZ + e;
        const float pz = accz[j][i][r] + bzv;
        const float ph = acch[j][i][r] + bhv;
        const float ex = __expf(-pz);
        const float z  = 1.0f / (1.0f + ex);
        const __bf16 abf = (__bf16)fmaf(ex, z, 1e-8f);  // (1-z) + 1e-8
        const float  af2 = (float)abf;                   // rounded, matches pass3
        const float  bf2 = z * ph;
        a_ws[idx]  = abf;
        b_out[idx] = bf2;
        Bv = fmaf(af2, Bv, bf2);
        A *= af2;
      }
      Aseg[i] = A; Bseg[i] = Bv;
    }
    // scan across the 4 q-lanes (stride 16): q=3 holds the 16-row composition
    #pragma unroll
    for (int i = 0; i < 4; ++i) {
      #pragma unroll
      for (int s = 16; s < 64; s <<= 1) {
        const float Ap = __shfl_up(Aseg[i], s, 64);
        const float Bp = __shfl_up(Bseg[i], s, 64);
        if (lane >= s) { Bseg[i] = fmaf(Aseg[i], Bp, Bseg[i]); Aseg[i] *= Ap; }
      }
    }
    if (q == 3) {
      #pragma unroll
      for (int c = 0; c < 2; ++c) {
        const float Ac = Aseg[2*c+1] * Aseg[2*c];
        const float Bc = fmaf(Aseg[2*c+1], Bseg[2*c], Bseg[2*c+1]);
        const int bc = (M0 + wM + c*32) >> 5;   // = b*NC + chunk (NC=128)
        Aprod[(size_t)bc*DSZ + e] = Ac;
        Bcomp[(size_t)bc*DSZ + e] = Bc;
      }
    }
  }
}

// ---------------- scan pass 2: wave64 shuffle scan, 2 chunks per lane --------
__global__ void scan_pass2_kernel(const float* __restrict__ Aprod,
                                  const float* __restrict__ Bcomp,
                                  float* __restrict__ Hstart)
{
  const int lane = threadIdx.x & 63;
  const int wave = (blockIdx.x * 256 + threadIdx.x) >> 6;  // 0..4095
  const int b = wave >> 10;
  const int d = wave & 1023;
  const size_t i0 = (size_t)(b*NC + 2*lane)*DSZ + d;
  const float A0 = Aprod[i0],       B0 = Bcomp[i0];
  const float A1 = Aprod[i0 + DSZ], B1 = Bcomp[i0 + DSZ];
  float A  = A0 * A1;               // pair compose: chunk 2l then 2l+1
  float Bv = fmaf(A1, B0, B1);
  #pragma unroll
  for (int s = 1; s < 64; s <<= 1) {
    const float Ap = __shfl_up(A,  s, 64);
    const float Bp = __shfl_up(Bv, s, 64);
    if (lane >= s) { Bv = fmaf(A, Bp, Bv); A *= Ap; }
  }
  float Hp = __shfl_up(Bv, 1, 64);  // exclusive: h at start of chunk 2l
  if (lane == 0) Hp = 0.0f;
  Hstart[i0]       = Hp;
  Hstart[i0 + DSZ] = fmaf(A0, Hp, B0);  // h at start of chunk 2l+1
}

// ---------------- scan pass 3: apply within chunk (4 d per thread) -----------
__global__ void scan_pass3_kernel(const __bf16* __restrict__ a_ws,
                                  const float* __restrict__ Hstart,
                                  float* __restrict__ out)
{
  const int bc   = blockIdx.x;
  const int d0   = threadIdx.x * 4;
  const size_t base = (size_t)bc * CH * DSZ + d0;
  float4 hv = *(const float4*)(Hstart + (size_t)bc*DSZ + d0);
  float h[4] = {hv.x, hv.y, hv.z, hv.w};
  #pragma unroll 8
  for (int t = 0; t < CH; ++t) {
    bf16x4 a4 = *(const bf16x4*)(a_ws + base + (size_t)t*DSZ);
    float4 b4 = *(const float4*)(out + base + (size_t)t*DSZ);
    const float bb[4] = {b4.x, b4.y, b4.z, b4.w};
    #pragma unroll
    for (int c = 0; c < 4; ++c)
      h[c] = fmaf((float)a4[c], h[c], bb[c]);
    *(float4*)(out + base + (size_t)t*DSZ) = make_float4(h[0], h[1], h[2], h[3]);
  }
}

extern "C" void kernel_launch(void* const* d_in, const int* in_sizes, int n_in,
                              void* d_out, int out_size, void* d_ws, size_t ws_size,
                              hipStream_t stream)
{
  const float* x  = (const float*)d_in[0];
  const float* Wz = (const float*)d_in[1];
  const float* bz = (const float*)d_in[2];
  const float* Wh = (const float*)d_in[3];
  const float* bh = (const float*)d_in[4];
  float* out = (float*)d_out;

  // ws layout: Xc (32MB) | Wzc (2MB) | Whc (2MB) | a (32MB) | Aprod|Bcomp|Hstart (2MB each)
  __bf16* Xc   = (__bf16*)d_ws;
  __bf16* Wzc  = Xc  + (size_t)MSZ * DSZ;
  __bf16* Whc  = Wzc + (size_t)DSZ * DSZ;
  __bf16* a_ws = Whc + (size_t)DSZ * DSZ;
  float* Aprod  = (float*)(a_ws + (size_t)MSZ * DSZ);
  float* Bcomp  = Aprod + (size_t)BSZ*NC*DSZ;
  float* Hstart = Bcomp + (size_t)BSZ*NC*DSZ;

  convert_tile_kernel<<<4608, 256, 0, stream>>>(x, Wz, Wh, Xc, Wzc, Whc);
  gemm_gate_kernel<<<dim3(8, 128), 256, 0, stream>>>(
      Xc, Wzc, Whc, bz, bh, a_ws, out, Aprod, Bcomp);
  scan_pass2_kernel<<<(BSZ*DSZ)/4, 256, 0, stream>>>(Aprod, Bcomp, Hstart);
  scan_pass3_kernel<<<BSZ*NC, 256, 0, stream>>>(a_ws, Hstart, out);
}